// Round 4
// baseline (511.573 us; speedup 1.0000x reference)
//
#include <hip/hip_runtime.h>
#include <math.h>

#define HDIM 1024
#define VDIM 50257
#define LDIM 512
#define NBLK 1024

// ws layout (floats)
#define WS_BAR    0      // 5 barrier slots x 16 uints (use as uint*)
#define WS_ATTLOG 128    // [128,640)   attention logits
#define WS_CTX    768    // [768,1792)  attn_applied (atomicAdd accum)
#define WS_X      1792   // [1792,2816) GRU input x
#define WS_GH     2816   // [2816,5888) gh = h@W_hh.T + b_hh
#define WS_BUCK   5888   // [5888,5952) 64 exp-sum buckets
#define WS_HNEW   5952   // [5952,6976) h_new

__device__ __forceinline__ float waveSum(float v) {
#pragma unroll
    for (int o = 32; o; o >>= 1) v += __shfl_down(v, o, 64);
    return v;
}

// agent-scope (device-coherent) scalar access — safe across non-coherent XCD L2s
__device__ __forceinline__ void stA(float* p, float v) {
    __hip_atomic_store(p, v, __ATOMIC_RELAXED, __HIP_MEMORY_SCOPE_AGENT);
}
__device__ __forceinline__ float ldA(const float* p) {
    return __hip_atomic_load(p, __ATOMIC_RELAXED, __HIP_MEMORY_SCOPE_AGENT);
}

__device__ __forceinline__ void gridbar(unsigned* bar, int slot) {
    __syncthreads();
    if (threadIdx.x == 0) {
        unsigned* p = bar + slot * 16;
        __hip_atomic_fetch_add(p, 1u, __ATOMIC_ACQ_REL, __HIP_MEMORY_SCOPE_AGENT);
        int guard = 0;
        while (__hip_atomic_load(p, __ATOMIC_ACQUIRE, __HIP_MEMORY_SCOPE_AGENT) < NBLK) {
            __builtin_amdgcn_s_sleep(2);
            if (++guard > 20000000) break;   // bail instead of hanging the harness
        }
    }
    __syncthreads();
}

// prologue: zero barrier slots + atomic accumulators (every call — replay-safe)
__global__ __launch_bounds__(256) void k_zero(float* __restrict__ ws) {
    int t = threadIdx.x;
    unsigned* bar = (unsigned*)ws;
    if (t < 80) bar[t] = 0u;
    ws[WS_CTX + t] = 0.f; ws[WS_CTX + 256 + t] = 0.f;
    ws[WS_CTX + 512 + t] = 0.f; ws[WS_CTX + 768 + t] = 0.f;
    if (t < 64) ws[WS_BUCK + t] = 0.f;
}

__global__ __launch_bounds__(256, 4) void k_main(
    const int* __restrict__ idx_p, const float* __restrict__ hidden,
    const float* __restrict__ emb, const float* __restrict__ attn_W,
    const float* __restrict__ attn_b, const float* __restrict__ enc,
    const float* __restrict__ comb_W, const float* __restrict__ comb_b,
    const float* __restrict__ W_ih, const float* __restrict__ W_hh,
    const float* __restrict__ b_ih, const float* __restrict__ b_hh,
    const float* __restrict__ out_W, const float* __restrict__ out_b,
    float* __restrict__ ws, float* __restrict__ out)
{
    const int blk = blockIdx.x, t = threadIdx.x;
    const int wid = t >> 6, lane = t & 63;
    __shared__ __align__(16) float sbuf[1024];
    __shared__ float sred[4];
    unsigned* bar = (unsigned*)ws;
    const float4* h4 = (const float4*)hidden;

    // ---------- P0: attn logits (blk 0..127) + gh (blk 128..895) ----------
    if (blk < 128) {
        const float4* e4 = (const float4*)(emb + (size_t)idx_p[0] * HDIM);
        int row = blk * 4 + wid;                       // 0..511
        const float4* w4 = (const float4*)(attn_W + (size_t)row * 2 * HDIM);
        float acc = 0.f;
#pragma unroll
        for (int k = 0; k < 8; ++k) {
            int c = lane + 64 * k;                     // float4 chunk 0..511
            float4 w = w4[c];
            float4 x = (c < 256) ? e4[c] : h4[c - 256];
            acc += w.x * x.x + w.y * x.y + w.z * x.z + w.w * x.w;
        }
        acc = waveSum(acc);
        if (lane == 0) stA(ws + WS_ATTLOG + row, acc + attn_b[row]);
    } else if (blk < 896) {
        int k = (blk - 128) * 4 + wid;                 // 0..3071
        const float4* w4 = (const float4*)(W_hh + (size_t)k * HDIM);
        float acc = 0.f;
#pragma unroll
        for (int q = 0; q < 4; ++q) {
            int c = lane + 64 * q;
            float4 w = w4[c]; float4 x = h4[c];
            acc += w.x * x.x + w.y * x.y + w.z * x.z + w.w * x.w;
        }
        acc = waveSum(acc);
        if (lane == 0) stA(ws + WS_GH + k, acc + b_hh[k]);
    }
    gridbar(bar, 0);

    // ---------- P1: redundant softmax(512) + context / attn-weight output ----------
    if (blk < 65) {
        float v0 = ldA(ws + WS_ATTLOG + t);
        float v1 = ldA(ws + WS_ATTLOG + 256 + t);
        float m = fmaxf(v0, v1);
#pragma unroll
        for (int o = 32; o; o >>= 1) m = fmaxf(m, __shfl_down(m, o, 64));
        if (lane == 0) sred[wid] = m;
        __syncthreads();
        m = fmaxf(fmaxf(sred[0], sred[1]), fmaxf(sred[2], sred[3]));
        __syncthreads();
        float e0 = expf(v0 - m), e1 = expf(v1 - m);
        float s = waveSum(e0 + e1);
        if (lane == 0) sred[wid] = s;
        __syncthreads();
        s = sred[0] + sred[1] + sred[2] + sred[3];
        float inv = 1.f / s;
        sbuf[t] = e0 * inv; sbuf[256 + t] = e1 * inv;
        __syncthreads();
        if (blk == 64) {
            out[VDIM + HDIM + t] = sbuf[t];
            out[VDIM + HDIM + 256 + t] = sbuf[256 + t];
        } else {
            int lc = blk & 15, hb = blk >> 4;
            int h = hb * 256 + t;
            int l0 = lc * 32;
            float acc = 0.f;
#pragma unroll 8
            for (int j = 0; j < 32; ++j)
                acc += sbuf[l0 + j] * enc[(size_t)(l0 + j) * HDIM + h];
            atomicAdd(&ws[WS_CTX + h], acc);           // device-scope, coherent
        }
    }
    gridbar(bar, 1);

    // ---------- P2: combine -> x (blk 0..255) ----------
    if (blk < 256) {
        // stage ctx[1024] into LDS via coherent loads
        sbuf[t]       = ldA(ws + WS_CTX + t);
        sbuf[256 + t] = ldA(ws + WS_CTX + 256 + t);
        sbuf[512 + t] = ldA(ws + WS_CTX + 512 + t);
        sbuf[768 + t] = ldA(ws + WS_CTX + 768 + t);
        __syncthreads();
        const float4* s4 = (const float4*)sbuf;
        const float4* e4 = (const float4*)(emb + (size_t)idx_p[0] * HDIM);
        int j = blk * 4 + wid;                         // 0..1023
        const float4* w4 = (const float4*)(comb_W + (size_t)j * 2 * HDIM);
        float acc = 0.f;
#pragma unroll
        for (int k = 0; k < 8; ++k) {
            int c = lane + 64 * k;
            float4 w = w4[c];
            float4 x = (c < 256) ? e4[c] : s4[c - 256];
            acc += w.x * x.x + w.y * x.y + w.z * x.z + w.w * x.w;
        }
        acc = waveSum(acc);
        if (lane == 0) stA(ws + WS_X + j, fmaxf(acc + comb_b[j], 0.f));
    }
    gridbar(bar, 2);

    // ---------- P3: gi + GRU gate -> h_new (blk 0..255, wave per h-index) ----------
    if (blk < 256) {
        sbuf[t]       = ldA(ws + WS_X + t);
        sbuf[256 + t] = ldA(ws + WS_X + 256 + t);
        sbuf[512 + t] = ldA(ws + WS_X + 512 + t);
        sbuf[768 + t] = ldA(ws + WS_X + 768 + t);
        __syncthreads();
        const float4* s4 = (const float4*)sbuf;
        int i = blk * 4 + wid;                         // 0..1023
        float a0 = 0.f, a1 = 0.f, a2 = 0.f;
#pragma unroll
        for (int q = 0; q < 4; ++q) {
            int c = lane + 64 * q;
            float4 x = s4[c];
            const float4* wr = (const float4*)(W_ih + (size_t)i * HDIM);
            const float4* wz = (const float4*)(W_ih + (size_t)(HDIM + i) * HDIM);
            const float4* wn = (const float4*)(W_ih + (size_t)(2 * HDIM + i) * HDIM);
            float4 w0 = wr[c], w1 = wz[c], w2 = wn[c];
            a0 += w0.x * x.x + w0.y * x.y + w0.z * x.z + w0.w * x.w;
            a1 += w1.x * x.x + w1.y * x.y + w1.z * x.z + w1.w * x.w;
            a2 += w2.x * x.x + w2.y * x.y + w2.z * x.z + w2.w * x.w;
        }
        a0 = waveSum(a0); a1 = waveSum(a1); a2 = waveSum(a2);
        if (lane == 0) {
            float gi_r = a0 + b_ih[i];
            float gi_z = a1 + b_ih[HDIM + i];
            float gi_n = a2 + b_ih[2 * HDIM + i];
            float gh_r = ldA(ws + WS_GH + i);
            float gh_z = ldA(ws + WS_GH + HDIM + i);
            float gh_n = ldA(ws + WS_GH + 2 * HDIM + i);
            float r_ = 1.f / (1.f + expf(-(gi_r + gh_r)));
            float z  = 1.f / (1.f + expf(-(gi_z + gh_z)));
            float n  = tanhf(gi_n + r_ * gh_n);
            float hn = (1.f - z) * n + z * hidden[i];
            stA(ws + WS_HNEW + i, hn);
            out[VDIM + i] = hn;
        }
    }
    gridbar(bar, 3);

    // ---------- P4: V-matvec, all blocks; per-block exp partials ----------
    {
        sbuf[t]       = ldA(ws + WS_HNEW + t);
        sbuf[256 + t] = ldA(ws + WS_HNEW + 256 + t);
        sbuf[512 + t] = ldA(ws + WS_HNEW + 512 + t);
        sbuf[768 + t] = ldA(ws + WS_HNEW + 768 + t);
        __syncthreads();
        const float4* s4 = (const float4*)sbuf;
        float esum = 0.f;                              // lane0 of each wave
        for (int v = blk * 4 + wid; v < VDIM; v += NBLK * 4) {
            const float4* w4 = (const float4*)(out_W + (size_t)v * HDIM);
            float acc = 0.f;
#pragma unroll
            for (int q = 0; q < 4; ++q) {
                int c = lane + 64 * q;
                float4 w = w4[c]; float4 x = s4[c];
                acc += w.x * x.x + w.y * x.y + w.z * x.z + w.w * x.w;
            }
            acc = waveSum(acc);
            if (lane == 0) {
                float logit = acc + out_b[v];
                out[v] = logit;
                esum += expf(logit);
            }
        }
        __syncthreads();                               // sbuf reuse below
        if (lane == 0) sbuf[wid] = esum;
        __syncthreads();
        if (t == 0) {
            float bsum = sbuf[0] + sbuf[1] + sbuf[2] + sbuf[3];
            __hip_atomic_fetch_add(&ws[WS_BUCK + (blk & 63)], bsum,
                                   __ATOMIC_RELEASE, __HIP_MEMORY_SCOPE_AGENT);
        }
    }
    gridbar(bar, 4);

    // ---------- P5: LSE + normalize own rows ----------
    {
        if (t < 64) {
            float b = waveSum(ldA(ws + WS_BUCK + t));
            if (t == 0) sred[0] = logf(b);
        }
        __syncthreads();
        float lse = sred[0];
        if (lane == 0)
            for (int v = blk * 4 + wid; v < VDIM; v += NBLK * 4)
                out[v] -= lse;                         // same-block data: L2-local
    }
}

extern "C" void kernel_launch(void* const* d_in, const int* in_sizes, int n_in,
                              void* d_out, int out_size, void* d_ws, size_t ws_size,
                              hipStream_t stream) {
    const int*   idx    = (const int*)d_in[0];
    const float* hidden = (const float*)d_in[1];
    const float* enc    = (const float*)d_in[2];
    const float* emb    = (const float*)d_in[3];
    const float* attn_W = (const float*)d_in[4];
    const float* attn_b = (const float*)d_in[5];
    const float* comb_W = (const float*)d_in[6];
    const float* comb_b = (const float*)d_in[7];
    const float* W_ih   = (const float*)d_in[8];
    const float* W_hh   = (const float*)d_in[9];
    const float* b_ih   = (const float*)d_in[10];
    const float* b_hh   = (const float*)d_in[11];
    const float* out_W  = (const float*)d_in[12];
    const float* out_b  = (const float*)d_in[13];

    float* out = (float*)d_out;                 // [V logits][H h_new][L attn_w]
    float* ws  = (float*)d_ws;

    k_zero<<<1, 256, 0, stream>>>(ws);
    k_main<<<NBLK, 256, 0, stream>>>(idx, hidden, emb, attn_W, attn_b, enc,
                                     comb_W, comb_b, W_ih, W_hh, b_ih, b_hh,
                                     out_W, out_b, ws, out);
}

// Round 5
// 184.697 us; speedup vs baseline: 2.7698x; 2.7698x over previous
//
#include <hip/hip_runtime.h>
#include <math.h>

#define HDIM 1024
#define VDIM 50257
#define LDIM 512
#define GRID 12565          // ceil(VDIM/4) — one vocab row per wave

// worker block ranges (all < 1024 guaranteed-co-resident blocks)
#define P0_BLKS 512         // attn logits + gh
#define P1_LO   512         // 65 blocks: softmax + ctx
#define P1_HI   577
#define P2_LO   577         // 128 blocks: combine -> x
#define P2_HI   705
#define P3_LO   705         // 128 blocks: gi + gate -> h_new
#define P3_HI   833

// ws layout (floats); flags are uints at the front, 32-uint (128 B) spacing
#define WS_FLAG   0         // [0,128) uints: 4 slots
#define WS_ATTLOG 128       // [128,640)
#define WS_CTX    768       // [768,1792)   atomicAdd accum (zeroed by k_zero)
#define WS_X      1792      // [1792,2816)
#define WS_GH     2816      // [2816,5888)
#define WS_HNEW   5888      // [5888,6912)
#define WS_BUCK   6912      // [6912,6976)  exp-sum buckets (zeroed by k_zero)

__device__ __forceinline__ float waveSum(float v) {
#pragma unroll
    for (int o = 32; o; o >>= 1) v += __shfl_down(v, o, 64);
    return v;
}

// Consumer: relaxed polls (no cache invalidation per poll), ONE acquire at the end.
__device__ __forceinline__ void waitFlag(unsigned* flags, int slot, unsigned target) {
    if (threadIdx.x == 0) {
        unsigned* p = flags + slot * 32;
        int guard = 0;
        while (__hip_atomic_load(p, __ATOMIC_RELAXED, __HIP_MEMORY_SCOPE_AGENT) < target) {
            __builtin_amdgcn_s_sleep(8);
            if (++guard > 1000000) break;      // bail instead of hanging harness
        }
        __hip_atomic_load(p, __ATOMIC_ACQUIRE, __HIP_MEMORY_SCOPE_AGENT);
    }
    __syncthreads();
}

// Producer: __syncthreads drains the block's stores, then one release increment.
__device__ __forceinline__ void postFlag(unsigned* flags, int slot) {
    __syncthreads();
    if (threadIdx.x == 0)
        __hip_atomic_fetch_add(flags + slot * 32, 1u, __ATOMIC_RELEASE,
                               __HIP_MEMORY_SCOPE_AGENT);
}

// prologue: zero flags + atomic accumulators (every call — replay-safe)
__global__ __launch_bounds__(256) void k_zero(float* __restrict__ ws) {
    int t = threadIdx.x;
    unsigned* flags = (unsigned*)ws;
    if (t < 128) flags[t] = 0u;
    ws[WS_CTX + t] = 0.f; ws[WS_CTX + 256 + t] = 0.f;
    ws[WS_CTX + 512 + t] = 0.f; ws[WS_CTX + 768 + t] = 0.f;
    if (t < 64) ws[WS_BUCK + t] = 0.f;
}

__global__ __launch_bounds__(256, 4) void k_main(
    const int* __restrict__ idx_p, const float* __restrict__ hidden,
    const float* __restrict__ emb, const float* __restrict__ attn_W,
    const float* __restrict__ attn_b, const float* __restrict__ enc,
    const float* __restrict__ comb_W, const float* __restrict__ comb_b,
    const float* __restrict__ W_ih, const float* __restrict__ W_hh,
    const float* __restrict__ b_ih, const float* __restrict__ b_hh,
    const float* __restrict__ out_W, const float* __restrict__ out_b,
    float* __restrict__ ws, float* __restrict__ out)
{
    const int blk = blockIdx.x, t = threadIdx.x;
    const int wid = t >> 6, lane = t & 63;
    __shared__ __align__(16) float sbuf[1024];
    __shared__ float sred[4];
    unsigned* flags = (unsigned*)ws;
    const float4* h4 = (const float4*)hidden;

    // ---- prefetch this block's V-matvec operands (immutable inputs) ----
    int vrow = blk * 4 + wid;
    int v_eff = vrow < VDIM ? vrow : VDIM - 1;
    const float4* wp = (const float4*)(out_W + (size_t)v_eff * HDIM);
    float4 pw0 = wp[lane], pw1 = wp[lane + 64], pw2 = wp[lane + 128], pw3 = wp[lane + 192];
    float pb = out_b[v_eff];

    // ---------- P0: attn logits (waves 0..511) + gh (waves 512..2047) ----------
    if (blk < P0_BLKS) {
        int W = blk * 4 + wid;                          // 0..2047
        if (W < 512) {
            const float4* e4 = (const float4*)(emb + (size_t)idx_p[0] * HDIM);
            const float4* w4 = (const float4*)(attn_W + (size_t)W * 2 * HDIM);
            float acc = 0.f;
#pragma unroll
            for (int k = 0; k < 8; ++k) {
                int c = lane + 64 * k;                  // float4 chunk 0..511
                float4 w = w4[c];
                float4 x = (c < 256) ? e4[c] : h4[c - 256];
                acc += w.x * x.x + w.y * x.y + w.z * x.z + w.w * x.w;
            }
            acc = waveSum(acc);
            if (lane == 0) ws[WS_ATTLOG + W] = acc + attn_b[W];
        } else {
#pragma unroll
            for (int rr = 0; rr < 2; ++rr) {
                int k = (W - 512) * 2 + rr;             // 0..3071
                const float4* w4 = (const float4*)(W_hh + (size_t)k * HDIM);
                float acc = 0.f;
#pragma unroll
                for (int q = 0; q < 4; ++q) {
                    int c = lane + 64 * q;
                    float4 w = w4[c]; float4 x = h4[c];
                    acc += w.x * x.x + w.y * x.y + w.z * x.z + w.w * x.w;
                }
                acc = waveSum(acc);
                if (lane == 0) ws[WS_GH + k] = acc + b_hh[k];
            }
        }
        postFlag(flags, 0);
    }
    // ---------- P1: redundant softmax(512) + ctx / attn-weight out ----------
    else if (blk < P1_HI) {
        waitFlag(flags, 0, P0_BLKS);
        int b = blk - P1_LO;                            // 0..64
        float v0 = ws[WS_ATTLOG + t], v1 = ws[WS_ATTLOG + 256 + t];
        float m = fmaxf(v0, v1);
#pragma unroll
        for (int o = 32; o; o >>= 1) m = fmaxf(m, __shfl_down(m, o, 64));
        if (lane == 0) sred[wid] = m;
        __syncthreads();
        m = fmaxf(fmaxf(sred[0], sred[1]), fmaxf(sred[2], sred[3]));
        __syncthreads();
        float e0 = expf(v0 - m), e1 = expf(v1 - m);
        float s = waveSum(e0 + e1);
        if (lane == 0) sred[wid] = s;
        __syncthreads();
        s = sred[0] + sred[1] + sred[2] + sred[3];
        float inv = 1.f / s;
        sbuf[t] = e0 * inv; sbuf[256 + t] = e1 * inv;
        __syncthreads();
        if (b == 64) {
            out[VDIM + HDIM + t] = sbuf[t];
            out[VDIM + HDIM + 256 + t] = sbuf[256 + t];
        } else {
            int lc = b & 15, hb = b >> 4;
            int h = hb * 256 + t;
            int l0 = lc * 32;
            float acc = 0.f;
#pragma unroll 8
            for (int j = 0; j < 32; ++j)
                acc += sbuf[l0 + j] * enc[(size_t)(l0 + j) * HDIM + h];
            atomicAdd(&ws[WS_CTX + h], acc);            // device-scope
        }
        postFlag(flags, 1);
    }
    // ---------- P2: combine -> x ----------
    else if (blk < P2_HI) {
        waitFlag(flags, 1, P1_HI - P1_LO);
        sbuf[t]       = ws[WS_CTX + t];
        sbuf[256 + t] = ws[WS_CTX + 256 + t];
        sbuf[512 + t] = ws[WS_CTX + 512 + t];
        sbuf[768 + t] = ws[WS_CTX + 768 + t];
        __syncthreads();
        const float4* s4 = (const float4*)sbuf;
        const float4* e4 = (const float4*)(emb + (size_t)idx_p[0] * HDIM);
#pragma unroll
        for (int rr = 0; rr < 2; ++rr) {
            int j = (blk - P2_LO) * 4 + wid + rr * 512; // 0..1023
            const float4* w4 = (const float4*)(comb_W + (size_t)j * 2 * HDIM);
            float acc = 0.f;
#pragma unroll
            for (int k = 0; k < 8; ++k) {
                int c = lane + 64 * k;
                float4 w = w4[c];
                float4 x = (c < 256) ? e4[c] : s4[c - 256];
                acc += w.x * x.x + w.y * x.y + w.z * x.z + w.w * x.w;
            }
            acc = waveSum(acc);
            if (lane == 0) ws[WS_X + j] = fmaxf(acc + comb_b[j], 0.f);
        }
        postFlag(flags, 2);
    }
    // ---------- P3: gi + GRU gate -> h_new ----------
    else if (blk < P3_HI) {
        waitFlag(flags, 2, P2_HI - P2_LO);
        sbuf[t]       = ws[WS_X + t];
        sbuf[256 + t] = ws[WS_X + 256 + t];
        sbuf[512 + t] = ws[WS_X + 512 + t];
        sbuf[768 + t] = ws[WS_X + 768 + t];
        __syncthreads();
        const float4* s4 = (const float4*)sbuf;
#pragma unroll
        for (int rr = 0; rr < 2; ++rr) {
            int i = (blk - P3_LO) * 4 + wid + rr * 512; // 0..1023
            float a0 = 0.f, a1 = 0.f, a2 = 0.f;
            const float4* wr = (const float4*)(W_ih + (size_t)i * HDIM);
            const float4* wz = (const float4*)(W_ih + (size_t)(HDIM + i) * HDIM);
            const float4* wn = (const float4*)(W_ih + (size_t)(2 * HDIM + i) * HDIM);
#pragma unroll
            for (int q = 0; q < 4; ++q) {
                int c = lane + 64 * q;
                float4 x = s4[c];
                float4 w0 = wr[c], w1 = wz[c], w2 = wn[c];
                a0 += w0.x * x.x + w0.y * x.y + w0.z * x.z + w0.w * x.w;
                a1 += w1.x * x.x + w1.y * x.y + w1.z * x.z + w1.w * x.w;
                a2 += w2.x * x.x + w2.y * x.y + w2.z * x.z + w2.w * x.w;
            }
            a0 = waveSum(a0); a1 = waveSum(a1); a2 = waveSum(a2);
            if (lane == 0) {
                float gi_r = a0 + b_ih[i];
                float gi_z = a1 + b_ih[HDIM + i];
                float gi_n = a2 + b_ih[2 * HDIM + i];
                float gh_r = ws[WS_GH + i];
                float gh_z = ws[WS_GH + HDIM + i];
                float gh_n = ws[WS_GH + 2 * HDIM + i];
                float r_ = 1.f / (1.f + expf(-(gi_r + gh_r)));
                float z  = 1.f / (1.f + expf(-(gi_z + gh_z)));
                float n  = tanhf(gi_n + r_ * gh_n);
                float hn = (1.f - z) * n + z * hidden[i];
                ws[WS_HNEW + i] = hn;
                out[VDIM + i]   = hn;
            }
        }
        postFlag(flags, 3);
    }

    // ---------- P4: V-matvec (all blocks) + exp buckets ----------
    waitFlag(flags, 3, P3_HI - P3_LO);
    sbuf[t]       = ws[WS_HNEW + t];
    sbuf[256 + t] = ws[WS_HNEW + 256 + t];
    sbuf[512 + t] = ws[WS_HNEW + 512 + t];
    sbuf[768 + t] = ws[WS_HNEW + 768 + t];
    __syncthreads();
    const float4* s4 = (const float4*)sbuf;
    {
        float4 x0 = s4[lane], x1 = s4[lane + 64], x2 = s4[lane + 128], x3 = s4[lane + 192];
        float acc = pw0.x * x0.x + pw0.y * x0.y + pw0.z * x0.z + pw0.w * x0.w
                  + pw1.x * x1.x + pw1.y * x1.y + pw1.z * x1.z + pw1.w * x1.w
                  + pw2.x * x2.x + pw2.y * x2.y + pw2.z * x2.z + pw2.w * x2.w
                  + pw3.x * x3.x + pw3.y * x3.y + pw3.z * x3.z + pw3.w * x3.w;
        acc = waveSum(acc);
        if (lane == 0) {
            if (vrow < VDIM) {
                float logit = acc + pb;
                out[vrow] = logit;
                sred[wid] = expf(logit);
            } else {
                sred[wid] = 0.f;
            }
        }
    }
    __syncthreads();
    if (t == 0)
        atomicAdd(&ws[WS_BUCK + (blk & 63)], sred[0] + sred[1] + sred[2] + sred[3]);
}

// normalize: out[i] -= log(sum of buckets)
__global__ __launch_bounds__(256) void k_final(const float* __restrict__ ws,
                                               float* __restrict__ out) {
    __shared__ float s_ls;
    const int t = threadIdx.x;
    if (t < 64) {
        float b = waveSum(ws[WS_BUCK + t]);
        if (t == 0) s_ls = logf(b);
    }
    __syncthreads();
    int i = blockIdx.x * 256 + t;
    if (i < VDIM) out[i] -= s_ls;
}

extern "C" void kernel_launch(void* const* d_in, const int* in_sizes, int n_in,
                              void* d_out, int out_size, void* d_ws, size_t ws_size,
                              hipStream_t stream) {
    const int*   idx    = (const int*)d_in[0];
    const float* hidden = (const float*)d_in[1];
    const float* enc    = (const float*)d_in[2];
    const float* emb    = (const float*)d_in[3];
    const float* attn_W = (const float*)d_in[4];
    const float* attn_b = (const float*)d_in[5];
    const float* comb_W = (const float*)d_in[6];
    const float* comb_b = (const float*)d_in[7];
    const float* W_ih   = (const float*)d_in[8];
    const float* W_hh   = (const float*)d_in[9];
    const float* b_ih   = (const float*)d_in[10];
    const float* b_hh   = (const float*)d_in[11];
    const float* out_W  = (const float*)d_in[12];
    const float* out_b  = (const float*)d_in[13];

    float* out = (float*)d_out;                 // [V logits][H h_new][L attn_w]
    float* ws  = (float*)d_ws;

    k_zero<<<1, 256, 0, stream>>>(ws);
    k_main<<<GRID, 256, 0, stream>>>(idx, hidden, emb, attn_W, attn_b, enc,
                                     comb_W, comb_b, W_ih, W_hh, b_ih, b_hh,
                                     out_W, out_b, ws, out);
    k_final<<<(VDIM + 255) / 256, 256, 0, stream>>>(ws, out);
}

// Round 6
// 104.338 us; speedup vs baseline: 4.9030x; 1.7702x over previous
//
#include <hip/hip_runtime.h>
#include <math.h>

#define HDIM 1024
#define VDIM 50257
#define LDIM 512

// ws float offsets (all 16B-aligned)
#define WS_ATTLOG 0      // [0,512)     attention logits
#define WS_CTX    512    // [512,1536)  attn_applied (atomicAdd accum)
#define WS_X      1536   // [1536,2560) GRU input x
#define WS_GH     2560   // [2560,5632) gh = h@W_hh.T + b_hh
#define WS_BUCK   5632   // [5632,5696) 64 exp-sum buckets
#define WS_HNEW   5696   // [5696,6720) h_new

__device__ __forceinline__ float waveSum(float v) {
#pragma unroll
    for (int o = 32; o; o >>= 1) v += __shfl_down(v, o, 64);
    return v;
}

// K1: attn logits (blocks 0..127) + gh rows (blocks 128..895) + zero accums (block 0)
__global__ __launch_bounds__(256) void k1(const int* __restrict__ idx_p,
                                          const float* __restrict__ hidden,
                                          const float* __restrict__ emb,
                                          const float* __restrict__ attn_W,
                                          const float* __restrict__ attn_b,
                                          const float* __restrict__ W_hh,
                                          const float* __restrict__ b_hh,
                                          float* __restrict__ ws) {
    const int blk = blockIdx.x, t = threadIdx.x;
    const int wid = t >> 6, lane = t & 63;
    if (blk == 0) {
        ws[WS_CTX + t] = 0.f; ws[WS_CTX + 256 + t] = 0.f;
        ws[WS_CTX + 512 + t] = 0.f; ws[WS_CTX + 768 + t] = 0.f;
        if (t < 64) ws[WS_BUCK + t] = 0.f;
    }
    const float4* h4 = (const float4*)hidden;
    if (blk < 128) {
        const float4* e4 = (const float4*)(emb + (size_t)idx_p[0] * HDIM);
        int row = blk * 4 + wid;                        // 0..511
        const float4* w4 = (const float4*)(attn_W + (size_t)row * 2 * HDIM);
        float acc = 0.f;
#pragma unroll
        for (int k = 0; k < 8; ++k) {
            int c = lane + 64 * k;                      // float4 chunk 0..511
            float4 w = w4[c];
            float4 x = (c < 256) ? e4[c] : h4[c - 256];
            acc += w.x * x.x + w.y * x.y + w.z * x.z + w.w * x.w;
        }
        acc = waveSum(acc);
        if (lane == 0) ws[WS_ATTLOG + row] = acc + attn_b[row];
    } else {
        int k = (blk - 128) * 4 + wid;                  // 0..3071
        const float4* w4 = (const float4*)(W_hh + (size_t)k * HDIM);
        float acc = 0.f;
#pragma unroll
        for (int q = 0; q < 4; ++q) {
            int c = lane + 64 * q;
            float4 w = w4[c]; float4 x = h4[c];
            acc += w.x * x.x + w.y * x.y + w.z * x.z + w.w * x.w;
        }
        acc = waveSum(acc);
        if (lane == 0) ws[WS_GH + k] = acc + b_hh[k];
    }
}

// K2: redundant softmax(512) per block; blocks 0..127: ctx slice (16 L-rows x 256 H);
//     block 128: attention-weights output.
__global__ __launch_bounds__(256) void k2(const float* __restrict__ enc,
                                          float* __restrict__ ws,
                                          float* __restrict__ out) {
    __shared__ float sred[4];
    __shared__ float sW[512];
    const int blk = blockIdx.x, t = threadIdx.x;
    const int wid = t >> 6, lane = t & 63;
    float v0 = ws[WS_ATTLOG + t], v1 = ws[WS_ATTLOG + 256 + t];
    float m = fmaxf(v0, v1);
#pragma unroll
    for (int o = 32; o; o >>= 1) m = fmaxf(m, __shfl_down(m, o, 64));
    if (lane == 0) sred[wid] = m;
    __syncthreads();
    m = fmaxf(fmaxf(sred[0], sred[1]), fmaxf(sred[2], sred[3]));
    __syncthreads();
    float e0 = expf(v0 - m), e1 = expf(v1 - m);
    float s = waveSum(e0 + e1);
    if (lane == 0) sred[wid] = s;
    __syncthreads();
    s = sred[0] + sred[1] + sred[2] + sred[3];
    float inv = 1.f / s;
    sW[t] = e0 * inv; sW[256 + t] = e1 * inv;
    __syncthreads();
    if (blk == 128) {
        out[VDIM + HDIM + t] = sW[t];
        out[VDIM + HDIM + 256 + t] = sW[256 + t];
    } else {
        int lc = blk & 31, hb = blk >> 5;               // 32 L-chunks x 4 H-chunks
        int h = hb * 256 + t;
        int l0 = lc * 16;
        float acc = 0.f;
#pragma unroll 8
        for (int j = 0; j < 16; ++j)
            acc += sW[l0 + j] * enc[(size_t)(l0 + j) * HDIM + h];
        atomicAdd(&ws[WS_CTX + h], acc);
    }
}

// K3: x[j] = relu(dot(cat(emb_row, ctx), comb_W[j]) + comb_b[j]); 256 blocks x 4 waves
__global__ __launch_bounds__(256) void k3(const int* __restrict__ idx_p,
                                          const float* __restrict__ emb,
                                          const float* __restrict__ comb_W,
                                          const float* __restrict__ comb_b,
                                          float* __restrict__ ws) {
    const int t = threadIdx.x, wid = t >> 6, lane = t & 63;
    int j = blockIdx.x * 4 + wid;                       // 0..1023
    const float4* w4 = (const float4*)(comb_W + (size_t)j * 2 * HDIM);
    const float4* e4 = (const float4*)(emb + (size_t)idx_p[0] * HDIM);
    const float4* c4 = (const float4*)(ws + WS_CTX);
    float acc = 0.f;
#pragma unroll
    for (int k = 0; k < 8; ++k) {
        int c = lane + 64 * k;
        float4 w = w4[c];
        float4 x = (c < 256) ? e4[c] : c4[c - 256];
        acc += w.x * x.x + w.y * x.y + w.z * x.z + w.w * x.w;
    }
    acc = waveSum(acc);
    if (lane == 0) ws[WS_X + j] = fmaxf(acc + comb_b[j], 0.f);
}

// K4: gi + GRU gate, one h-index per 192-thread block (3 waves = 3 gate rows).
__global__ __launch_bounds__(192) void k4(const float* __restrict__ hidden,
                                          const float* __restrict__ W_ih,
                                          const float* __restrict__ b_ih,
                                          float* __restrict__ ws,
                                          float* __restrict__ out) {
    __shared__ float sg[3];
    const int i = blockIdx.x;                           // h index 0..1023
    const int t = threadIdx.x, r = t >> 6, lane = t & 63;
    const float4* w4 = (const float4*)(W_ih + (size_t)(r * HDIM + i) * HDIM);
    const float4* x4 = (const float4*)(ws + WS_X);
    float acc = 0.f;
#pragma unroll
    for (int q = 0; q < 4; ++q) {
        int c = lane + 64 * q;
        float4 w = w4[c]; float4 x = x4[c];
        acc += w.x * x.x + w.y * x.y + w.z * x.z + w.w * x.w;
    }
    acc = waveSum(acc);
    if (lane == 0) sg[r] = acc + b_ih[r * HDIM + i];
    __syncthreads();
    if (t == 0) {
        float gh_r = ws[WS_GH + i];
        float gh_z = ws[WS_GH + HDIM + i];
        float gh_n = ws[WS_GH + 2 * HDIM + i];
        float r_ = 1.f / (1.f + expf(-(sg[0] + gh_r)));
        float z  = 1.f / (1.f + expf(-(sg[1] + gh_z)));
        float n  = tanhf(sg[2] + r_ * gh_n);
        float hn = (1.f - z) * n + z * hidden[i];
        ws[WS_HNEW + i] = hn;
        out[VDIM + i]   = hn;
    }
}

// K5: V-matvec (one vocab row per wave) + per-block exp partials into 64 buckets.
__global__ __launch_bounds__(256) void k5(const float* __restrict__ out_W,
                                          const float* __restrict__ out_b,
                                          float* __restrict__ ws,
                                          float* __restrict__ out) {
    __shared__ float se[4];
    const int t = threadIdx.x, wid = t >> 6, lane = t & 63;
    int v = blockIdx.x * 4 + wid;
    const float4* h4 = (const float4*)(ws + WS_HNEW);
    if (v < VDIM) {
        const float4* w4 = (const float4*)(out_W + (size_t)v * HDIM);
        float acc = 0.f;
#pragma unroll
        for (int q = 0; q < 4; ++q) {
            int c = lane + 64 * q;
            float4 w = w4[c]; float4 x = h4[c];
            acc += w.x * x.x + w.y * x.y + w.z * x.z + w.w * x.w;
        }
        acc = waveSum(acc);
        if (lane == 0) {
            float logit = acc + out_b[v];
            out[v] = logit;
            se[wid] = expf(logit);
        }
    } else if (lane == 0) {
        se[wid] = 0.f;
    }
    __syncthreads();
    if (t == 0)
        atomicAdd(&ws[WS_BUCK + (blockIdx.x & 63)], se[0] + se[1] + se[2] + se[3]);
}

// K6: out[i] -= log(sum of buckets)
__global__ __launch_bounds__(256) void k6(const float* __restrict__ ws,
                                          float* __restrict__ out) {
    __shared__ float s_ls;
    const int t = threadIdx.x;
    if (t < 64) {
        float b = waveSum(ws[WS_BUCK + t]);
        if (t == 0) s_ls = logf(b);
    }
    __syncthreads();
    int i = blockIdx.x * 256 + t;
    if (i < VDIM) out[i] -= s_ls;
}

extern "C" void kernel_launch(void* const* d_in, const int* in_sizes, int n_in,
                              void* d_out, int out_size, void* d_ws, size_t ws_size,
                              hipStream_t stream) {
    const int*   idx    = (const int*)d_in[0];
    const float* hidden = (const float*)d_in[1];
    const float* enc    = (const float*)d_in[2];
    const float* emb    = (const float*)d_in[3];
    const float* attn_W = (const float*)d_in[4];
    const float* attn_b = (const float*)d_in[5];
    const float* comb_W = (const float*)d_in[6];
    const float* comb_b = (const float*)d_in[7];
    const float* W_ih   = (const float*)d_in[8];
    const float* W_hh   = (const float*)d_in[9];
    const float* b_ih   = (const float*)d_in[10];
    const float* b_hh   = (const float*)d_in[11];
    const float* out_W  = (const float*)d_in[12];
    const float* out_b  = (const float*)d_in[13];

    float* out = (float*)d_out;                 // [V logits][H h_new][L attn_w]
    float* ws  = (float*)d_ws;

    k1<<<896, 256, 0, stream>>>(idx, hidden, emb, attn_W, attn_b, W_hh, b_hh, ws);
    k2<<<129, 256, 0, stream>>>(enc, ws, out);
    k3<<<256, 256, 0, stream>>>(idx, emb, comb_W, comb_b, ws);
    k4<<<1024, 192, 0, stream>>>(hidden, W_ih, b_ih, ws, out);
    k5<<<(VDIM + 3) / 4, 256, 0, stream>>>(out_W, out_b, ws, out);
    k6<<<(VDIM + 255) / 256, 256, 0, stream>>>(ws, out);
}

// Round 7
// 56.328 us; speedup vs baseline: 9.0820x; 1.8523x over previous
//
#include <hip/hip_runtime.h>
#include <math.h>

#define HDIM 1024
#define VDIM 50257
#define LDIM 512

// ws float offsets (all 16B-aligned)
#define WS_ATTLOG 0      // [0,512)       attention logits
#define WS_CTXP   512    // [512,8704)    ctx partials [8][1024] (plain stores)
#define WS_X      8704   // [8704,9728)   GRU input x
#define WS_GH     9728   // [9728,12800)  gh = h@W_hh.T + b_hh
#define WS_HNEW   12800  // [12800,13824) h_new
#define WS_BUCK   13824  // [13824,15872) 128 exp-sum buckets, stride 16 (1/cacheline)

__device__ __forceinline__ float waveSum(float v) {
#pragma unroll
    for (int o = 32; o; o >>= 1) v += __shfl_down(v, o, 64);
    return v;
}

// K1: attn logits (blocks 0..127) + gh rows (blocks 128..895); block 0 zeros buckets
__global__ __launch_bounds__(256) void k1(const int* __restrict__ idx_p,
                                          const float* __restrict__ hidden,
                                          const float* __restrict__ emb,
                                          const float* __restrict__ attn_W,
                                          const float* __restrict__ attn_b,
                                          const float* __restrict__ W_hh,
                                          const float* __restrict__ b_hh,
                                          float* __restrict__ ws) {
    const int blk = blockIdx.x, t = threadIdx.x;
    const int wid = t >> 6, lane = t & 63;
    if (blk == 0) {
#pragma unroll
        for (int r = 0; r < 8; ++r) ws[WS_BUCK + r * 256 + t] = 0.f;
    }
    const float4* h4 = (const float4*)hidden;
    if (blk < 128) {
        const float4* e4 = (const float4*)(emb + (size_t)idx_p[0] * HDIM);
        int row = blk * 4 + wid;                        // 0..511
        const float4* w4 = (const float4*)(attn_W + (size_t)row * 2 * HDIM);
        float acc = 0.f;
#pragma unroll
        for (int k = 0; k < 8; ++k) {
            int c = lane + 64 * k;                      // float4 chunk 0..511
            float4 w = w4[c];
            float4 x = (c < 256) ? e4[c] : h4[c - 256];
            acc += w.x * x.x + w.y * x.y + w.z * x.z + w.w * x.w;
        }
        acc = waveSum(acc);
        if (lane == 0) ws[WS_ATTLOG + row] = acc + attn_b[row];
    } else {
        int k = (blk - 128) * 4 + wid;                  // 0..3071
        const float4* w4 = (const float4*)(W_hh + (size_t)k * HDIM);
        float acc = 0.f;
#pragma unroll
        for (int q = 0; q < 4; ++q) {
            int c = lane + 64 * q;
            float4 w = w4[c]; float4 x = h4[c];
            acc += w.x * x.x + w.y * x.y + w.z * x.z + w.w * x.w;
        }
        acc = waveSum(acc);
        if (lane == 0) ws[WS_GH + k] = acc + b_hh[k];
    }
}

// K2: redundant softmax(512) per block; blocks 0..31: ctx partial (lc-chunk of 64 L-rows
//     x 256 h, plain store); block 32: attention-weights output. No atomics.
__global__ __launch_bounds__(256) void k2(const float* __restrict__ enc,
                                          float* __restrict__ ws,
                                          float* __restrict__ out) {
    __shared__ float sred[4];
    __shared__ float sW[512];
    const int blk = blockIdx.x, t = threadIdx.x;
    const int wid = t >> 6, lane = t & 63;
    float v0 = ws[WS_ATTLOG + t], v1 = ws[WS_ATTLOG + 256 + t];
    float m = fmaxf(v0, v1);
#pragma unroll
    for (int o = 32; o; o >>= 1) m = fmaxf(m, __shfl_down(m, o, 64));
    if (lane == 0) sred[wid] = m;
    __syncthreads();
    m = fmaxf(fmaxf(sred[0], sred[1]), fmaxf(sred[2], sred[3]));
    __syncthreads();
    float e0 = expf(v0 - m), e1 = expf(v1 - m);
    float s = waveSum(e0 + e1);
    if (lane == 0) sred[wid] = s;
    __syncthreads();
    s = sred[0] + sred[1] + sred[2] + sred[3];
    float inv = 1.f / s;
    sW[t] = e0 * inv; sW[256 + t] = e1 * inv;
    __syncthreads();
    if (blk == 32) {
        out[VDIM + HDIM + t] = sW[t];
        out[VDIM + HDIM + 256 + t] = sW[256 + t];
    } else {
        int lc = blk & 7, hb = blk >> 3;                // 8 L-chunks x 4 H-chunks
        int h = hb * 256 + t;
        int l0 = lc * 64;
        float acc = 0.f;
#pragma unroll 8
        for (int j = 0; j < 64; ++j)
            acc += sW[l0 + j] * enc[(size_t)(l0 + j) * HDIM + h];
        ws[WS_CTXP + lc * HDIM + h] = acc;              // plain store
    }
}

// K3: sum 8 ctx partials into LDS, then x[j] = relu(dot(cat(emb,ctx), comb_W[j]) + b)
__global__ __launch_bounds__(256) void k3(const int* __restrict__ idx_p,
                                          const float* __restrict__ emb,
                                          const float* __restrict__ comb_W,
                                          const float* __restrict__ comb_b,
                                          float* __restrict__ ws) {
    __shared__ __align__(16) float sctx[1024];
    const int t = threadIdx.x, wid = t >> 6, lane = t & 63;
    {   // thread t sums partials for float4 chunk t (h = 4t..4t+3)
        const float4* p4 = (const float4*)(ws + WS_CTXP);
        float4 a = p4[t];
#pragma unroll
        for (int p = 1; p < 8; ++p) {
            float4 b = p4[p * 256 + t];
            a.x += b.x; a.y += b.y; a.z += b.z; a.w += b.w;
        }
        ((float4*)sctx)[t] = a;
    }
    __syncthreads();
    int j = blockIdx.x * 4 + wid;                       // 0..1023
    const float4* w4 = (const float4*)(comb_W + (size_t)j * 2 * HDIM);
    const float4* e4 = (const float4*)(emb + (size_t)idx_p[0] * HDIM);
    const float4* c4 = (const float4*)sctx;
    float acc = 0.f;
#pragma unroll
    for (int k = 0; k < 8; ++k) {
        int c = lane + 64 * k;
        float4 w = w4[c];
        float4 x = (c < 256) ? e4[c] : c4[c - 256];
        acc += w.x * x.x + w.y * x.y + w.z * x.z + w.w * x.w;
    }
    acc = waveSum(acc);
    if (lane == 0) ws[WS_X + j] = fmaxf(acc + comb_b[j], 0.f);
}

// K4: gi + GRU gate, one h-index per 192-thread block (3 waves = 3 gate rows).
__global__ __launch_bounds__(192) void k4(const float* __restrict__ hidden,
                                          const float* __restrict__ W_ih,
                                          const float* __restrict__ b_ih,
                                          float* __restrict__ ws,
                                          float* __restrict__ out) {
    __shared__ float sg[3];
    const int i = blockIdx.x;                           // h index 0..1023
    const int t = threadIdx.x, r = t >> 6, lane = t & 63;
    const float4* w4 = (const float4*)(W_ih + (size_t)(r * HDIM + i) * HDIM);
    const float4* x4 = (const float4*)(ws + WS_X);
    float acc = 0.f;
#pragma unroll
    for (int q = 0; q < 4; ++q) {
        int c = lane + 64 * q;
        float4 w = w4[c]; float4 x = x4[c];
        acc += w.x * x.x + w.y * x.y + w.z * x.z + w.w * x.w;
    }
    acc = waveSum(acc);
    if (lane == 0) sg[r] = acc + b_ih[r * HDIM + i];
    __syncthreads();
    if (t == 0) {
        float gh_r = ws[WS_GH + i];
        float gh_z = ws[WS_GH + HDIM + i];
        float gh_n = ws[WS_GH + 2 * HDIM + i];
        float r_ = 1.f / (1.f + expf(-(sg[0] + gh_r)));
        float z  = 1.f / (1.f + expf(-(sg[1] + gh_z)));
        float n  = tanhf(sg[2] + r_ * gh_n);
        float hn = (1.f - z) * n + z * hidden[i];
        ws[WS_HNEW + i] = hn;
        out[VDIM + i]   = hn;
    }
}

// K5: V-matvec (one vocab row per wave) + per-block exp partial into a
//     cacheline-private bucket (128 buckets, stride 16 floats).
__global__ __launch_bounds__(256) void k5(const float* __restrict__ out_W,
                                          const float* __restrict__ out_b,
                                          float* __restrict__ ws,
                                          float* __restrict__ out) {
    __shared__ float se[4];
    const int t = threadIdx.x, wid = t >> 6, lane = t & 63;
    int v = blockIdx.x * 4 + wid;
    const float4* h4 = (const float4*)(ws + WS_HNEW);
    if (v < VDIM) {
        const float4* w4 = (const float4*)(out_W + (size_t)v * HDIM);
        float acc = 0.f;
#pragma unroll
        for (int q = 0; q < 4; ++q) {
            int c = lane + 64 * q;
            float4 w = w4[c]; float4 x = h4[c];
            acc += w.x * x.x + w.y * x.y + w.z * x.z + w.w * x.w;
        }
        acc = waveSum(acc);
        if (lane == 0) {
            float logit = acc + out_b[v];
            out[v] = logit;
            se[wid] = expf(logit);
        }
    } else if (lane == 0) {
        se[wid] = 0.f;
    }
    __syncthreads();
    if (t == 0)
        atomicAdd(&ws[WS_BUCK + (blockIdx.x & 127) * 16],
                  se[0] + se[1] + se[2] + se[3]);
}

// K6: out[i] -= log(sum of 128 strided buckets)
__global__ __launch_bounds__(256) void k6(const float* __restrict__ ws,
                                          float* __restrict__ out) {
    __shared__ float sls[2];
    const int t = threadIdx.x, wid = t >> 6, lane = t & 63;
    if (t < 128) {
        float b = waveSum(ws[WS_BUCK + t * 16]);
        if (lane == 0) sls[wid] = b;
    }
    __syncthreads();
    float ls = logf(sls[0] + sls[1]);
    int i = blockIdx.x * 256 + t;
    if (i < VDIM) out[i] -= ls;
}

extern "C" void kernel_launch(void* const* d_in, const int* in_sizes, int n_in,
                              void* d_out, int out_size, void* d_ws, size_t ws_size,
                              hipStream_t stream) {
    const int*   idx    = (const int*)d_in[0];
    const float* hidden = (const float*)d_in[1];
    const float* enc    = (const float*)d_in[2];
    const float* emb    = (const float*)d_in[3];
    const float* attn_W = (const float*)d_in[4];
    const float* attn_b = (const float*)d_in[5];
    const float* comb_W = (const float*)d_in[6];
    const float* comb_b = (const float*)d_in[7];
    const float* W_ih   = (const float*)d_in[8];
    const float* W_hh   = (const float*)d_in[9];
    const float* b_ih   = (const float*)d_in[10];
    const float* b_hh   = (const float*)d_in[11];
    const float* out_W  = (const float*)d_in[12];
    const float* out_b  = (const float*)d_in[13];

    float* out = (float*)d_out;                 // [V logits][H h_new][L attn_w]
    float* ws  = (float*)d_ws;

    k1<<<896, 256, 0, stream>>>(idx, hidden, emb, attn_W, attn_b, W_hh, b_hh, ws);
    k2<<<33, 256, 0, stream>>>(enc, ws, out);
    k3<<<256, 256, 0, stream>>>(idx, emb, comb_W, comb_b, ws);
    k4<<<1024, 192, 0, stream>>>(hidden, W_ih, b_ih, ws, out);
    k5<<<(VDIM + 3) / 4, 256, 0, stream>>>(out_W, out_b, ws, out);
    k6<<<(VDIM + 255) / 256, 256, 0, stream>>>(ws, out);
}